// Round 8
// baseline (335.037 us; speedup 1.0000x reference)
//
#include <hip/hip_runtime.h>
#include <hip/hip_bf16.h>

typedef short bf16x8 __attribute__((ext_vector_type(8)));
typedef float f32x4 __attribute__((ext_vector_type(4)));
typedef unsigned int u32;
typedef unsigned int u32x2 __attribute__((ext_vector_type(2)));

#define MFMA16 __builtin_amdgcn_mfma_f32_16x16x32_bf16
#define SCALE 0.17677669529663687f  // 1/sqrt(32)
#define LOG2E 1.4426950408889634f

// ws layout (bytes):
//   wqkv  bf16 [576][192]          @ 0        (221184)   (q rows pre-scaled by SCALE*LOG2E)
//   wproj bf16 [192][192]          @ 221184   (73728)
//   biasar f32 [6][16][64][4]      @ 294912   (98304)    (pre-scaled by LOG2E)
//   bq    f32  [576]               @ 393216   (2304)
//   Os    frag dump                @ 395520   (100663296)   [split path only]
#define OS_OFF 395520
#define WS_NEED (395520 + 100663296)

__device__ __forceinline__ unsigned short f2b(float x) {
  u32 u = __float_as_uint(x);
  u = (u + 0x7FFFu + ((u >> 16) & 1u)) >> 16;
  return (unsigned short)u;
}
__device__ __forceinline__ u32 pk2(float a, float b) {
  __hip_bfloat162 h = __float22bfloat162_rn(float2{a, b});
  return *(u32*)&h;
}
__device__ __forceinline__ uint2 pk4(f32x4 v) {
  return make_uint2(pk2(v[0], v[1]), pk2(v[2], v[3]));
}

// C-frag pair -> A/B-frag bf16x8 via 2x v_permlane16_swap (VALU). The k-dim
// carries a fixed permutation pi; pi is identical for every operand produced
// by this helper, so it cancels inside MFMA dot products.
__device__ __forceinline__ bf16x8 xpose(f32x4 a0, f32x4 a1) {
  u32 s0 = pk2(a0[0], a0[1]);
  u32 s1 = pk2(a0[2], a0[3]);
  u32 s2 = pk2(a1[0], a1[1]);
  u32 s3 = pk2(a1[2], a1[3]);
  u32x2 r0 = __builtin_amdgcn_permlane16_swap(s0, s2, false, false);
  u32x2 r1 = __builtin_amdgcn_permlane16_swap(s1, s3, false, false);
  union {
    u32 w[4];
    bf16x8 v;
  } u;
  u.w[0] = r0[0];
  u.w[1] = r1[0];
  u.w[2] = r0[1];
  u.w[3] = r1[1];
  return u.v;
}

__global__ void prep_kernel(const float* __restrict__ qkv_w, const float* __restrict__ qkv_b,
                            const float* __restrict__ proj_w, const float* __restrict__ rpb,
                            unsigned short* __restrict__ wqkv, unsigned short* __restrict__ wproj,
                            float* __restrict__ biasar, float* __restrict__ bq) {
  int i0 = blockIdx.x * blockDim.x + threadIdx.x;
  int stride = gridDim.x * blockDim.x;
  for (int i = i0; i < 576 * 192; i += stride) {
    float v = qkv_w[i];
    if (i < 192 * 192) v *= SCALE * LOG2E;  // q rows: fold softmax scale + log2(e)
    wqkv[i] = f2b(v);
  }
  for (int i = i0; i < 192 * 192; i += stride) wproj[i] = f2b(proj_w[i]);
  for (int i = i0; i < 576; i += stride) {
    float v = qkv_b[i];
    if (i < 192) v *= SCALE * LOG2E;
    bq[i] = v;
  }
  for (int i = i0; i < 6 * 16 * 64 * 4; i += stride) {
    int r = i & 3;
    int lane = (i >> 2) & 63;
    int fid = (i >> 8) & 15;
    int h = i >> 12;
    int mt = fid >> 2, nt = fid & 3;
    int m = mt * 16 + (lane >> 4) * 4 + r;
    int n = nt * 16 + (lane & 15);
    int idx = ((n >> 3) - (m >> 3) + 7) * 15 + ((n & 7) - (m & 7) + 7);
    biasar[i] = rpb[idx * 6 + h] * LOG2E;
  }
}

// ===================== SPLIT PATH =====================
// win_attn6: block = (window, head-group of 3) = 6 waves; wave = (head, q-half).
// half0 computes K, half1 computes V; frags exchanged via LDS. Q merged into
// the same kt loop (12 independent MFMA chains, shared x-frag reads).
// LDS: [0,24576) x bf16 [64 tok][384B rows] XOR-swizzled; [24576,49152) exchange.
__global__ void __launch_bounds__(384, 4) win_attn6(
    const float* __restrict__ x, const unsigned short* __restrict__ wqkv,
    const float* __restrict__ biasar, const float* __restrict__ bq,
    unsigned short* __restrict__ osout) {
  __shared__ __align__(16) char smem[49152];
  const int bid = blockIdx.x;
  const int b = bid >> 1;   // window
  const int hg = bid & 1;   // head group
  const int tid = threadIdx.x;
  const int wv = tid >> 6;       // 0..5
  const int hl = wv >> 1;        // head within block 0..2
  const int head = hg * 3 + hl;  // global head
  const int half = wv & 1;       // q-half
  const int lane = tid & 63;
  const int g = lane >> 4;
  const int c = lane & 15;
  char* xs = smem;
  char* exch = smem + 24576;

  // ---------- stage full x -> bf16 swizzled LDS ----------
  {
    const float* xb = x + (size_t)b * 12288;
#pragma unroll
    for (int it = 0; it < 8; ++it) {
      int idx = tid + it * 384;  // float4 index in [0,3072)
      int tok = idx / 48, c4 = idx % 48;
      float4 v = *(const float4*)(xb + tok * 192 + c4 * 4);
      *(uint2*)(xs + tok * 384 + (((c4 >> 1) ^ (tok & 7)) << 4) + (c4 & 1) * 8) =
          make_uint2(pk2(v.x, v.y), pk2(v.z, v.w));
    }
  }
  __syncthreads();

#define XF(tt, kt) \
  (*(const bf16x8*)(xs + ((tt) * 16 + c) * 384 + ((((kt) * 4 + g) ^ (c & 7)) << 4)))

  // ---------- merged Q + (K xor V) pass, bias as C-init ----------
  bf16x8 qb[2], ka[4], va[2][2];
  {
    const unsigned short* wq0 = wqkv + (size_t)(head * 32 + c) * 192 + 8 * g;
    const unsigned short* wq1 = wq0 + 16 * 192;
    f32x4 bq0 = *(const f32x4*)(bq + head * 32 + 4 * g);
    f32x4 bq1 = *(const f32x4*)(bq + head * 32 + 16 + 4 * g);
    f32x4 aq[2][2];
    aq[0][0] = bq0;
    aq[0][1] = bq0;
    aq[1][0] = bq1;
    aq[1][1] = bq1;
    char* ew = exch + hl * 8192 + half * 4096 + lane * 16;
    if (half == 0) {
      const unsigned short* wk0 = wqkv + (size_t)(192 + head * 32 + c) * 192 + 8 * g;
      const unsigned short* wk1 = wk0 + 16 * 192;
      f32x4 bk0 = *(const f32x4*)(bq + 192 + head * 32 + 4 * g);
      f32x4 bk1 = *(const f32x4*)(bq + 192 + head * 32 + 16 + 4 * g);
      f32x4 ak[2][4];
#pragma unroll
      for (int tt = 0; tt < 4; ++tt) {
        ak[0][tt] = bk0;
        ak[1][tt] = bk1;
      }
      __builtin_amdgcn_s_setprio(1);
#pragma unroll
      for (int kt = 0; kt < 6; ++kt) {
        bf16x8 xf0 = XF(0, kt), xf1 = XF(1, kt), xf2 = XF(2, kt), xf3 = XF(3, kt);
        bf16x8 q0 = *(const bf16x8*)(wq0 + kt * 32);
        bf16x8 q1 = *(const bf16x8*)(wq1 + kt * 32);
        bf16x8 k0 = *(const bf16x8*)(wk0 + kt * 32);
        bf16x8 k1 = *(const bf16x8*)(wk1 + kt * 32);
        bf16x8 xq0 = half ? xf2 : xf0;
        bf16x8 xq1 = half ? xf3 : xf1;
        aq[0][0] = MFMA16(q0, xq0, aq[0][0], 0, 0, 0);
        aq[1][0] = MFMA16(q1, xq0, aq[1][0], 0, 0, 0);
        aq[0][1] = MFMA16(q0, xq1, aq[0][1], 0, 0, 0);
        aq[1][1] = MFMA16(q1, xq1, aq[1][1], 0, 0, 0);
        ak[0][0] = MFMA16(k0, xf0, ak[0][0], 0, 0, 0);
        ak[1][0] = MFMA16(k1, xf0, ak[1][0], 0, 0, 0);
        ak[0][1] = MFMA16(k0, xf1, ak[0][1], 0, 0, 0);
        ak[1][1] = MFMA16(k1, xf1, ak[1][1], 0, 0, 0);
        ak[0][2] = MFMA16(k0, xf2, ak[0][2], 0, 0, 0);
        ak[1][2] = MFMA16(k1, xf2, ak[1][2], 0, 0, 0);
        ak[0][3] = MFMA16(k0, xf3, ak[0][3], 0, 0, 0);
        ak[1][3] = MFMA16(k1, xf3, ak[1][3], 0, 0, 0);
      }
      __builtin_amdgcn_s_setprio(0);
      qb[0] = xpose(aq[0][0], aq[1][0]);
      qb[1] = xpose(aq[0][1], aq[1][1]);
#pragma unroll
      for (int mt = 0; mt < 4; ++mt) {
        ka[mt] = xpose(ak[0][mt], ak[1][mt]);
        *(bf16x8*)(ew + mt * 1024) = ka[mt];
      }
    } else {
      const unsigned short* wv0 = wqkv + (size_t)(384 + head * 32 + c) * 192 + 8 * g;
      const unsigned short* wv1 = wv0 + 16 * 192;
      float bv0 = bq[384 + head * 32 + c];
      float bv1 = bq[384 + head * 32 + 16 + c];
      f32x4 av[4][2];
#pragma unroll
      for (int tt = 0; tt < 4; ++tt) {
        av[tt][0] = f32x4{bv0, bv0, bv0, bv0};
        av[tt][1] = f32x4{bv1, bv1, bv1, bv1};
      }
      __builtin_amdgcn_s_setprio(1);
#pragma unroll
      for (int kt = 0; kt < 6; ++kt) {
        bf16x8 xf0 = XF(0, kt), xf1 = XF(1, kt), xf2 = XF(2, kt), xf3 = XF(3, kt);
        bf16x8 q0 = *(const bf16x8*)(wq0 + kt * 32);
        bf16x8 q1 = *(const bf16x8*)(wq1 + kt * 32);
        bf16x8 v0 = *(const bf16x8*)(wv0 + kt * 32);
        bf16x8 v1 = *(const bf16x8*)(wv1 + kt * 32);
        bf16x8 xq0 = half ? xf2 : xf0;
        bf16x8 xq1 = half ? xf3 : xf1;
        aq[0][0] = MFMA16(q0, xq0, aq[0][0], 0, 0, 0);
        aq[1][0] = MFMA16(q1, xq0, aq[1][0], 0, 0, 0);
        aq[0][1] = MFMA16(q0, xq1, aq[0][1], 0, 0, 0);
        aq[1][1] = MFMA16(q1, xq1, aq[1][1], 0, 0, 0);
        av[0][0] = MFMA16(xf0, v0, av[0][0], 0, 0, 0);
        av[0][1] = MFMA16(xf0, v1, av[0][1], 0, 0, 0);
        av[1][0] = MFMA16(xf1, v0, av[1][0], 0, 0, 0);
        av[1][1] = MFMA16(xf1, v1, av[1][1], 0, 0, 0);
        av[2][0] = MFMA16(xf2, v0, av[2][0], 0, 0, 0);
        av[2][1] = MFMA16(xf2, v1, av[2][1], 0, 0, 0);
        av[3][0] = MFMA16(xf3, v0, av[3][0], 0, 0, 0);
        av[3][1] = MFMA16(xf3, v1, av[3][1], 0, 0, 0);
      }
      __builtin_amdgcn_s_setprio(0);
      qb[0] = xpose(aq[0][0], aq[1][0]);
      qb[1] = xpose(aq[0][1], aq[1][1]);
#pragma unroll
      for (int dt = 0; dt < 2; ++dt)
#pragma unroll
        for (int kh = 0; kh < 2; ++kh) {
          va[dt][kh] = xpose(av[2 * kh][dt], av[2 * kh + 1][dt]);
          *(bf16x8*)(ew + (dt * 2 + kh) * 1024) = va[dt][kh];
        }
    }
  }
  __syncthreads();
  {
    const char* er = exch + hl * 8192 + (half ^ 1) * 4096 + lane * 16;
    if (half == 0) {
#pragma unroll
      for (int f = 0; f < 4; ++f) va[f >> 1][f & 1] = *(const bf16x8*)(er + f * 1024);
    } else {
#pragma unroll
      for (int f = 0; f < 4; ++f) ka[f] = *(const bf16x8*)(er + f * 1024);
    }
  }

  // ---------- S = K @ Q^T (base-2 scaled) with bias as C operand; softmax ----------
  bf16x8 pbf[2][2];
  float linv[2];
  {
    const f32x4* bias4 = (const f32x4*)biasar + (size_t)(head * 16 + half * 2) * 64 + lane;
    f32x4 s[4][2];
    __builtin_amdgcn_s_setprio(1);
#pragma unroll
    for (int mt = 0; mt < 4; ++mt)
#pragma unroll
      for (int n2 = 0; n2 < 2; ++n2)
        s[mt][n2] = MFMA16(ka[mt], qb[n2], bias4[(mt * 4 + n2) * 64], 0, 0, 0);
    __builtin_amdgcn_s_setprio(0);
#pragma unroll
    for (int n2 = 0; n2 < 2; ++n2) {
      float mx = fmaxf(fmaxf(fmaxf(s[0][n2][0], s[0][n2][1]), fmaxf(s[0][n2][2], s[0][n2][3])),
                       fmaxf(fmaxf(s[1][n2][0], s[1][n2][1]), fmaxf(s[1][n2][2], s[1][n2][3])));
      mx = fmaxf(mx, fmaxf(fmaxf(fmaxf(s[2][n2][0], s[2][n2][1]), fmaxf(s[2][n2][2], s[2][n2][3])),
                           fmaxf(fmaxf(s[3][n2][0], s[3][n2][1]), fmaxf(s[3][n2][2], s[3][n2][3]))));
      mx = fmaxf(mx, __shfl_xor(mx, 16));
      mx = fmaxf(mx, __shfl_xor(mx, 32));
      float sum = 0.0f;
#pragma unroll
      for (int mt = 0; mt < 4; ++mt)
#pragma unroll
        for (int r = 0; r < 4; ++r) {
          float e = __builtin_exp2f(s[mt][n2][r] - mx);  // base-2: log2e folded upstream
          s[mt][n2][r] = e;
          sum += e;
        }
      sum += __shfl_xor(sum, 16);
      sum += __shfl_xor(sum, 32);
      linv[n2] = 1.0f / sum;
    }
#pragma unroll
    for (int n2 = 0; n2 < 2; ++n2) {
      pbf[0][n2] = xpose(s[0][n2], s[1][n2]);
      pbf[1][n2] = xpose(s[2][n2], s[3][n2]);
    }
  }

  // ---------- O^T = V^T @ P^T, scale, dump frags ----------
  f32x4 o[2][2];
#pragma unroll
  for (int dt = 0; dt < 2; ++dt)
#pragma unroll
    for (int n2 = 0; n2 < 2; ++n2) o[dt][n2] = (f32x4)0.0f;
  __builtin_amdgcn_s_setprio(1);
#pragma unroll
  for (int mh = 0; mh < 2; ++mh)
#pragma unroll
    for (int n2 = 0; n2 < 2; ++n2)
#pragma unroll
      for (int dt = 0; dt < 2; ++dt) o[dt][n2] = MFMA16(va[dt][mh], pbf[mh][n2], o[dt][n2], 0, 0, 0);
  __builtin_amdgcn_s_setprio(0);

  uint2* dst = (uint2*)osout + ((size_t)((b * 6 + head) * 2 + half) * 4) * 64 + lane;
#pragma unroll
  for (int dt = 0; dt < 2; ++dt)
#pragma unroll
    for (int n2 = 0; n2 < 2; ++n2) {
#pragma unroll
      for (int r = 0; r < 4; ++r) o[dt][n2][r] *= linv[n2];
      dst[(dt * 2 + n2) * 64] = pk4(o[dt][n2]);
    }
}

// proj: block = 1 window (64 tokens), 4 waves; wave w covers f in [w*48, w*48+48).
__global__ void __launch_bounds__(256, 4) proj_kernel(
    const unsigned short* __restrict__ osin, const unsigned short* __restrict__ wproj,
    const float* __restrict__ proj_b, float* __restrict__ out) {
  __shared__ __align__(16) char smem[24576];
  const int b = blockIdx.x;
  const int tid = threadIdx.x;
  const int w = tid >> 6;  // 0..3
  const int lane = tid & 63;
  const int g = lane >> 4;
  const int c = lane & 15;

  // ---------- decode frag dump -> [tok][d] swizzled LDS ----------
  {
    const uint2* src = (const uint2*)osin + (size_t)b * 3072;
#pragma unroll
    for (int it = 0; it < 12; ++it) {
      int i = tid + it * 256;
      int ls = i & 63;
      int f = (i >> 6) & 3;  // dt*2 + n2
      int unit = i >> 8;     // head*2 + half
      int head = unit >> 1, half = unit & 1;
      int dt = f >> 1, n2 = f & 1;
      int tok = half * 32 + n2 * 16 + (ls & 15);
      int d0 = head * 32 + dt * 16 + 4 * (ls >> 4);
      uint2 v = src[i];
      *(uint2*)(smem + tok * 384 + (((d0 >> 3) ^ (tok & 7)) << 4) + (d0 & 7) * 2) = v;
    }
  }
  __syncthreads();

  // ---------- GEMM: out = Os @ wproj^T + b ----------
  f32x4 acc[4][3];
#pragma unroll
  for (int mt = 0; mt < 4; ++mt)
#pragma unroll
    for (int ft = 0; ft < 3; ++ft) acc[mt][ft] = (f32x4)0.0f;
#pragma unroll
  for (int kt = 0; kt < 6; ++kt) {
    bf16x8 wf[3];
#pragma unroll
    for (int ft = 0; ft < 3; ++ft)
      wf[ft] = *(const bf16x8*)(wproj + (size_t)(w * 48 + ft * 16 + c) * 192 + kt * 32 + 8 * g);
#pragma unroll
    for (int mt = 0; mt < 4; ++mt) {
      bf16x8 of = *(const bf16x8*)(smem + (mt * 16 + c) * 384 + (((kt * 4 + g) ^ (c & 7)) << 4));
#pragma unroll
      for (int ft = 0; ft < 3; ++ft) acc[mt][ft] = MFMA16(of, wf[ft], acc[mt][ft], 0, 0, 0);
    }
  }
  float* outb = out + (size_t)b * 12288;
#pragma unroll
  for (int ft = 0; ft < 3; ++ft) {
    float pbv = proj_b[w * 48 + ft * 16 + c];
#pragma unroll
    for (int mt = 0; mt < 4; ++mt)
#pragma unroll
      for (int r = 0; r < 4; ++r)
        outb[(mt * 16 + 4 * g + r) * 192 + w * 48 + ft * 16 + c] = acc[mt][ft][r] + pbv;
  }
}

// ===================== FUSED FALLBACK (R4-based; exp2 tables) =====================
#define XFRAGOLD(tt, kt) \
  (*(const bf16x8*)(xs + ((tt) * 16 + c) * 384 + ((((kt) * 4 + g) ^ (c & 7)) << 4)))

__global__ void __launch_bounds__(384, 3) win_attn(
    const float* __restrict__ x, const unsigned short* __restrict__ wqkv,
    const unsigned short* __restrict__ wproj, const float* __restrict__ biasar,
    const float* __restrict__ bq, const float* __restrict__ proj_b, float* __restrict__ out) {
  __shared__ __align__(16) char smem[24576];
  const int b = blockIdx.x;
  const int tid = threadIdx.x;
  const int w = tid >> 6;
  const int lane = tid & 63;
  const int g = lane >> 4;
  const int c = lane & 15;
  char* xs = smem;

  {
    const float* xb = x + (size_t)b * 12288;
#pragma unroll
    for (int it = 0; it < 8; ++it) {
      int idx = tid + it * 384;
      int tok = idx / 48, c4 = idx % 48;
      float4 v = *(const float4*)(xb + tok * 192 + c4 * 4);
      *(uint2*)(xs + tok * 384 + (((c4 >> 1) ^ (tok & 7)) << 4) + (c4 & 1) * 8) =
          make_uint2(pk2(v.x, v.y), pk2(v.z, v.w));
    }
  }
  __syncthreads();

  bf16x8 qb[4];
  {
    f32x4 acc[2][4];
#pragma unroll
    for (int dt = 0; dt < 2; ++dt)
#pragma unroll
      for (int tt = 0; tt < 4; ++tt) acc[dt][tt] = (f32x4)0.0f;
#pragma unroll
    for (int kt = 0; kt < 6; ++kt) {
      bf16x8 wf[2];
#pragma unroll
      for (int dt = 0; dt < 2; ++dt)
        wf[dt] = *(const bf16x8*)(wqkv + (size_t)(w * 32 + dt * 16 + c) * 192 + kt * 32 + 8 * g);
#pragma unroll
      for (int tt = 0; tt < 4; ++tt) {
        bf16x8 xf = XFRAGOLD(tt, kt);
#pragma unroll
        for (int dt = 0; dt < 2; ++dt) acc[dt][tt] = MFMA16(wf[dt], xf, acc[dt][tt], 0, 0, 0);
      }
    }
#pragma unroll
    for (int dt = 0; dt < 2; ++dt)
#pragma unroll
      for (int r = 0; r < 4; ++r) {
        float bv = bq[w * 32 + dt * 16 + 4 * g + r];
#pragma unroll
        for (int tt = 0; tt < 4; ++tt) acc[dt][tt][r] += bv;
      }
#pragma unroll
    for (int nt = 0; nt < 4; ++nt) qb[nt] = xpose(acc[0][nt], acc[1][nt]);
  }

  bf16x8 ka[4];
  {
    f32x4 acc[2][4];
#pragma unroll
    for (int dt = 0; dt < 2; ++dt)
#pragma unroll
      for (int tt = 0; tt < 4; ++tt) acc[dt][tt] = (f32x4)0.0f;
#pragma unroll
    for (int kt = 0; kt < 6; ++kt) {
      bf16x8 wf[2];
#pragma unroll
      for (int dt = 0; dt < 2; ++dt)
        wf[dt] =
            *(const bf16x8*)(wqkv + (size_t)(192 + w * 32 + dt * 16 + c) * 192 + kt * 32 + 8 * g);
#pragma unroll
      for (int tt = 0; tt < 4; ++tt) {
        bf16x8 xf = XFRAGOLD(tt, kt);
#pragma unroll
        for (int dt = 0; dt < 2; ++dt) acc[dt][tt] = MFMA16(wf[dt], xf, acc[dt][tt], 0, 0, 0);
      }
    }
#pragma unroll
    for (int dt = 0; dt < 2; ++dt)
#pragma unroll
      for (int r = 0; r < 4; ++r) {
        float bv = bq[192 + w * 32 + dt * 16 + 4 * g + r];
#pragma unroll
        for (int tt = 0; tt < 4; ++tt) acc[dt][tt][r] += bv;
      }
#pragma unroll
    for (int mt = 0; mt < 4; ++mt) ka[mt] = xpose(acc[0][mt], acc[1][mt]);
  }

  bf16x8 pbf[2][4];
  float linv[4];
  const f32x4* bias4 = (const f32x4*)biasar;
#pragma unroll
  for (int h = 0; h < 2; ++h) {
    f32x4 s[4][2];
#pragma unroll
    for (int mt = 0; mt < 4; ++mt)
#pragma unroll
      for (int n2 = 0; n2 < 2; ++n2) {
        int nt = h * 2 + n2;
        f32x4 t = MFMA16(ka[mt], qb[nt], (f32x4)0.0f, 0, 0, 0);
        s[mt][n2] = t + bias4[(w * 16 + mt * 4 + nt) * 64 + lane];
      }
#pragma unroll
    for (int n2 = 0; n2 < 2; ++n2) {
      int nt = h * 2 + n2;
      float mx = -1e30f;
#pragma unroll
      for (int mt = 0; mt < 4; ++mt)
#pragma unroll
        for (int r = 0; r < 4; ++r) mx = fmaxf(mx, s[mt][n2][r]);
      mx = fmaxf(mx, __shfl_xor(mx, 16));
      mx = fmaxf(mx, __shfl_xor(mx, 32));
      float sum = 0.0f;
#pragma unroll
      for (int mt = 0; mt < 4; ++mt)
#pragma unroll
        for (int r = 0; r < 4; ++r) {
          float e = __builtin_exp2f(s[mt][n2][r] - mx);
          s[mt][n2][r] = e;
          sum += e;
        }
      sum += __shfl_xor(sum, 16);
      sum += __shfl_xor(sum, 32);
      linv[nt] = 1.0f / sum;
    }
#pragma unroll
    for (int n2 = 0; n2 < 2; ++n2) {
      pbf[0][h * 2 + n2] = xpose(s[0][n2], s[1][n2]);
      pbf[1][h * 2 + n2] = xpose(s[2][n2], s[3][n2]);
    }
  }

  bf16x8 va[2][2];
  {
    f32x4 acc[4][2];
#pragma unroll
    for (int mt = 0; mt < 4; ++mt)
#pragma unroll
      for (int dt = 0; dt < 2; ++dt) acc[mt][dt] = (f32x4)0.0f;
#pragma unroll
    for (int kt = 0; kt < 6; ++kt) {
      bf16x8 wf[2];
#pragma unroll
      for (int dt = 0; dt < 2; ++dt)
        wf[dt] =
            *(const bf16x8*)(wqkv + (size_t)(384 + w * 32 + dt * 16 + c) * 192 + kt * 32 + 8 * g);
#pragma unroll
      for (int tt = 0; tt < 4; ++tt) {
        bf16x8 xf = XFRAGOLD(tt, kt);
#pragma unroll
        for (int dt = 0; dt < 2; ++dt) acc[tt][dt] = MFMA16(xf, wf[dt], acc[tt][dt], 0, 0, 0);
      }
    }
#pragma unroll
    for (int dt = 0; dt < 2; ++dt) {
      float bv = bq[384 + w * 32 + dt * 16 + c];
#pragma unroll
      for (int mt = 0; mt < 4; ++mt)
#pragma unroll
        for (int r = 0; r < 4; ++r) acc[mt][dt][r] += bv;
    }
#pragma unroll
    for (int dt = 0; dt < 2; ++dt)
#pragma unroll
      for (int kh = 0; kh < 2; ++kh) va[dt][kh] = xpose(acc[2 * kh][dt], acc[2 * kh + 1][dt]);
  }

  f32x4 o[2][4];
#pragma unroll
  for (int dt = 0; dt < 2; ++dt)
#pragma unroll
    for (int nt = 0; nt < 4; ++nt) o[dt][nt] = (f32x4)0.0f;
#pragma unroll
  for (int mh = 0; mh < 2; ++mh)
#pragma unroll
    for (int nt = 0; nt < 4; ++nt)
#pragma unroll
      for (int dt = 0; dt < 2; ++dt) o[dt][nt] = MFMA16(va[dt][mh], pbf[mh][nt], o[dt][nt], 0, 0, 0);
#pragma unroll
  for (int dt = 0; dt < 2; ++dt)
#pragma unroll
    for (int nt = 0; nt < 4; ++nt)
#pragma unroll
      for (int r = 0; r < 4; ++r) o[dt][nt][r] *= linv[nt];

  __syncthreads();
#pragma unroll
  for (int dt = 0; dt < 2; ++dt)
#pragma unroll
    for (int nt = 0; nt < 4; ++nt)
      *(uint2*)(xs + (nt * 16 + c) * 384 + (((w * 4 + dt * 2 + (g >> 1)) ^ (c & 7)) << 4) +
                (g & 1) * 8) =
          make_uint2(pk2(o[dt][nt][0], o[dt][nt][1]), pk2(o[dt][nt][2], o[dt][nt][3]));
  __syncthreads();

  f32x4 accP[4][2];
#pragma unroll
  for (int mt = 0; mt < 4; ++mt)
#pragma unroll
    for (int ft = 0; ft < 2; ++ft) accP[mt][ft] = (f32x4)0.0f;
#pragma unroll
  for (int kt = 0; kt < 6; ++kt) {
    bf16x8 wp[2];
#pragma unroll
    for (int ft = 0; ft < 2; ++ft)
      wp[ft] = *(const bf16x8*)(wproj + (size_t)(w * 32 + ft * 16 + c) * 192 + kt * 32 + 8 * g);
#pragma unroll
    for (int mt = 0; mt < 4; ++mt) {
      bf16x8 of = *(const bf16x8*)(xs + (mt * 16 + c) * 384 + (((kt * 4 + g) ^ (c & 7)) << 4));
#pragma unroll
      for (int ft = 0; ft < 2; ++ft) accP[mt][ft] = MFMA16(of, wp[ft], accP[mt][ft], 0, 0, 0);
    }
  }
  float pb0 = proj_b[w * 32 + c];
  float pb1 = proj_b[w * 32 + 16 + c];
  float* outb = out + (size_t)b * 12288;
#pragma unroll
  for (int mt = 0; mt < 4; ++mt)
#pragma unroll
    for (int ft = 0; ft < 2; ++ft) {
      float pbv = ft ? pb1 : pb0;
#pragma unroll
      for (int r = 0; r < 4; ++r)
        outb[(mt * 16 + 4 * g + r) * 192 + w * 32 + ft * 16 + c] = accP[mt][ft][r] + pbv;
    }
}

extern "C" void kernel_launch(void* const* d_in, const int* in_sizes, int n_in,
                              void* d_out, int out_size, void* d_ws, size_t ws_size,
                              hipStream_t stream) {
  const float* x = (const float*)d_in[0];
  const float* qkv_w = (const float*)d_in[1];
  const float* qkv_b = (const float*)d_in[2];
  const float* proj_w = (const float*)d_in[3];
  const float* proj_b = (const float*)d_in[4];
  const float* rpb = (const float*)d_in[5];
  char* ws = (char*)d_ws;
  unsigned short* wqkv = (unsigned short*)ws;
  unsigned short* wproj = (unsigned short*)(ws + 221184);
  float* biasar = (float*)(ws + 294912);
  float* bqv = (float*)(ws + 393216);

  prep_kernel<<<432, 256, 0, stream>>>(qkv_w, qkv_b, proj_w, rpb, wqkv, wproj, biasar, bqv);

  if (ws_size >= (size_t)WS_NEED) {
    unsigned short* osbuf = (unsigned short*)(ws + OS_OFF);
    win_attn6<<<8192, 384, 0, stream>>>(x, wqkv, biasar, bqv, osbuf);
    proj_kernel<<<4096, 256, 0, stream>>>(osbuf, wproj, proj_b, (float*)d_out);
  } else {
    win_attn<<<4096, 384, 0, stream>>>(x, wqkv, wproj, biasar, bqv, proj_b, (float*)d_out);
  }
}

// Round 9
// 289.342 us; speedup vs baseline: 1.1579x; 1.1579x over previous
//
#include <hip/hip_runtime.h>
#include <hip/hip_bf16.h>

typedef short bf16x8 __attribute__((ext_vector_type(8)));
typedef float f32x4 __attribute__((ext_vector_type(4)));
typedef unsigned int u32;
typedef unsigned int u32x2 __attribute__((ext_vector_type(2)));

#define MFMA16 __builtin_amdgcn_mfma_f32_16x16x32_bf16
#define SCALE 0.17677669529663687f  // 1/sqrt(32)
#define LOG2E 1.4426950408889634f

// ws layout (bytes):
//   wqkv  bf16 [576][192]          @ 0        (221184)   (q rows pre-scaled by SCALE*LOG2E)
//   wproj bf16 [192][192]          @ 221184   (73728)
//   biasar f32 [6][16][64][4]      @ 294912   (98304)    (pre-scaled by LOG2E)
//   bq    f32  [576]               @ 393216   (2304)
//   Os    frag dump                @ 395520   (100663296)   [split path only]
#define OS_OFF 395520
#define WS_NEED (395520 + 100663296)

__device__ __forceinline__ unsigned short f2b(float x) {
  u32 u = __float_as_uint(x);
  u = (u + 0x7FFFu + ((u >> 16) & 1u)) >> 16;
  return (unsigned short)u;
}
__device__ __forceinline__ u32 pk2(float a, float b) {
  __hip_bfloat162 h = __float22bfloat162_rn(float2{a, b});
  return *(u32*)&h;
}
__device__ __forceinline__ uint2 pk4(f32x4 v) {
  return make_uint2(pk2(v[0], v[1]), pk2(v[2], v[3]));
}

// C-frag pair -> A/B-frag bf16x8 via 2x v_permlane16_swap (VALU). The k-dim
// carries a fixed permutation pi; pi is identical for every operand produced
// by this helper, so it cancels inside MFMA dot products.
__device__ __forceinline__ bf16x8 xpose(f32x4 a0, f32x4 a1) {
  u32 s0 = pk2(a0[0], a0[1]);
  u32 s1 = pk2(a0[2], a0[3]);
  u32 s2 = pk2(a1[0], a1[1]);
  u32 s3 = pk2(a1[2], a1[3]);
  u32x2 r0 = __builtin_amdgcn_permlane16_swap(s0, s2, false, false);
  u32x2 r1 = __builtin_amdgcn_permlane16_swap(s1, s3, false, false);
  union {
    u32 w[4];
    bf16x8 v;
  } u;
  u.w[0] = r0[0];
  u.w[1] = r1[0];
  u.w[2] = r0[1];
  u.w[3] = r1[1];
  return u.v;
}

__global__ void prep_kernel(const float* __restrict__ qkv_w, const float* __restrict__ qkv_b,
                            const float* __restrict__ proj_w, const float* __restrict__ rpb,
                            unsigned short* __restrict__ wqkv, unsigned short* __restrict__ wproj,
                            float* __restrict__ biasar, float* __restrict__ bq) {
  int i0 = blockIdx.x * blockDim.x + threadIdx.x;
  int stride = gridDim.x * blockDim.x;
  for (int i = i0; i < 576 * 192; i += stride) {
    float v = qkv_w[i];
    if (i < 192 * 192) v *= SCALE * LOG2E;  // q rows: fold softmax scale + log2(e)
    wqkv[i] = f2b(v);
  }
  for (int i = i0; i < 192 * 192; i += stride) wproj[i] = f2b(proj_w[i]);
  for (int i = i0; i < 576; i += stride) {
    float v = qkv_b[i];
    if (i < 192) v *= SCALE * LOG2E;
    bq[i] = v;
  }
  for (int i = i0; i < 6 * 16 * 64 * 4; i += stride) {
    int r = i & 3;
    int lane = (i >> 2) & 63;
    int fid = (i >> 8) & 15;
    int h = i >> 12;
    int mt = fid >> 2, nt = fid & 3;
    int m = mt * 16 + (lane >> 4) * 4 + r;
    int n = nt * 16 + (lane & 15);
    int idx = ((n >> 3) - (m >> 3) + 7) * 15 + ((n & 7) - (m & 7) + 7);
    biasar[i] = rpb[idx * 6 + h] * LOG2E;
  }
}

// ===================== SPLIT PATH =====================
// win_attn4: block = (window, head-pair hg of 3) = 4 waves (256 thr);
// wave = (head in pair, q-half). half0 computes K, half1 computes V; frags
// exchanged via LDS. R7's padded-row layout (zero VALU addressing; 8-way LDS
// aliasing is free in this latency-bound regime). Exchange buffer OVERLAYS the
// x tile (x is dead after the K/V pass; barrier separates) -> LDS 25.6KB ->
// 4 blocks/CU (16 waves) at the 128-reg cap. XCD swizzle keeps a window's 3
// sibling blocks on one XCD so the 3x x-staging mostly hits that XCD's L2.
__global__ void __launch_bounds__(256, 4) win_attn4(
    const float* __restrict__ x, const unsigned short* __restrict__ wqkv,
    const float* __restrict__ biasar, const float* __restrict__ bq,
    unsigned short* __restrict__ osout) {
  __shared__ __align__(16) char smem[25600];
  const int bid = blockIdx.x;
  const int xcd = bid & 7;
  const int local = bid >> 3;     // 0..1535
  const int wl = local / 3;       // 0..511
  const int hg = local - wl * 3;  // head pair 0..2
  const int b = xcd * 512 + wl;   // window
  const int tid = threadIdx.x;
  const int wv = tid >> 6;       // 0..3
  const int hl = wv >> 1;        // head within pair
  const int head = hg * 2 + hl;  // global head
  const int half = wv & 1;       // q-half
  const int lane = tid & 63;
  const int g = lane >> 4;
  const int c = lane & 15;
  char* xs = smem;
  char* exch = smem;  // overlays x (x dead after K/V pass; barrier-separated)

  // ---------- stage full x -> bf16 LDS, rows padded to 400B ----------
  {
    const float* xb = x + (size_t)b * 12288;
#pragma unroll
    for (int it = 0; it < 12; ++it) {
      int idx = tid + it * 256;  // float4 index in [0,3072)
      int tok = idx / 48, c4 = idx - tok * 48;
      float4 v = *(const float4*)(xb + tok * 192 + c4 * 4);
      *(uint2*)(xs + tok * 400 + c4 * 8) = make_uint2(pk2(v.x, v.y), pk2(v.z, v.w));
    }
  }
  __syncthreads();

  // ---------- Q pass (this wave's 32 query tokens; bias as C-init) ----------
  bf16x8 qb[2];
  {
    const unsigned short* wq0 = wqkv + (size_t)(head * 32 + c) * 192 + 8 * g;
    const unsigned short* wq1 = wq0 + 16 * 192;
    f32x4 a00 = *(const f32x4*)(bq + head * 32 + 4 * g);
    f32x4 a10 = *(const f32x4*)(bq + head * 32 + 16 + 4 * g);
    f32x4 a01 = a00, a11 = a10;
    const char* xr = xs + c * 400 + g * 16 + half * 12800;
#pragma unroll
    for (int kt = 0; kt < 6; ++kt) {
      bf16x8 x0 = *(const bf16x8*)(xr + kt * 64);
      bf16x8 x1 = *(const bf16x8*)(xr + 6400 + kt * 64);
      bf16x8 w0 = *(const bf16x8*)(wq0 + kt * 32);
      bf16x8 w1 = *(const bf16x8*)(wq1 + kt * 32);
      a00 = MFMA16(w0, x0, a00, 0, 0, 0);
      a10 = MFMA16(w1, x0, a10, 0, 0, 0);
      a01 = MFMA16(w0, x1, a01, 0, 0, 0);
      a11 = MFMA16(w1, x1, a11, 0, 0, 0);
    }
    qb[0] = xpose(a00, a10);
    qb[1] = xpose(a01, a11);
  }

  // ---------- K xor V pass (wave-uniform branch) ----------
  bf16x8 ka[4], va[2][2], own[4];
  {
    const char* xr = xs + c * 400 + g * 16;
    if (half == 0) {
      const unsigned short* wk0 = wqkv + (size_t)(192 + head * 32 + c) * 192 + 8 * g;
      const unsigned short* wk1 = wk0 + 16 * 192;
      f32x4 bk0 = *(const f32x4*)(bq + 192 + head * 32 + 4 * g);
      f32x4 bk1 = *(const f32x4*)(bq + 192 + head * 32 + 16 + 4 * g);
      f32x4 ak[2][4];
#pragma unroll
      for (int tt = 0; tt < 4; ++tt) {
        ak[0][tt] = bk0;
        ak[1][tt] = bk1;
      }
#pragma unroll
      for (int kt = 0; kt < 6; ++kt) {
        bf16x8 xf0 = *(const bf16x8*)(xr + kt * 64);
        bf16x8 xf1 = *(const bf16x8*)(xr + 6400 + kt * 64);
        bf16x8 xf2 = *(const bf16x8*)(xr + 12800 + kt * 64);
        bf16x8 xf3 = *(const bf16x8*)(xr + 19200 + kt * 64);
        bf16x8 w0 = *(const bf16x8*)(wk0 + kt * 32);
        bf16x8 w1 = *(const bf16x8*)(wk1 + kt * 32);
        ak[0][0] = MFMA16(w0, xf0, ak[0][0], 0, 0, 0);
        ak[1][0] = MFMA16(w1, xf0, ak[1][0], 0, 0, 0);
        ak[0][1] = MFMA16(w0, xf1, ak[0][1], 0, 0, 0);
        ak[1][1] = MFMA16(w1, xf1, ak[1][1], 0, 0, 0);
        ak[0][2] = MFMA16(w0, xf2, ak[0][2], 0, 0, 0);
        ak[1][2] = MFMA16(w1, xf2, ak[1][2], 0, 0, 0);
        ak[0][3] = MFMA16(w0, xf3, ak[0][3], 0, 0, 0);
        ak[1][3] = MFMA16(w1, xf3, ak[1][3], 0, 0, 0);
      }
#pragma unroll
      for (int mt = 0; mt < 4; ++mt) own[mt] = ka[mt] = xpose(ak[0][mt], ak[1][mt]);
    } else {
      const unsigned short* wv0 = wqkv + (size_t)(384 + head * 32 + c) * 192 + 8 * g;
      const unsigned short* wv1 = wv0 + 16 * 192;
      float bv0 = bq[384 + head * 32 + c];
      float bv1 = bq[384 + head * 32 + 16 + c];
      f32x4 av[4][2];
#pragma unroll
      for (int tt = 0; tt < 4; ++tt) {
        av[tt][0] = f32x4{bv0, bv0, bv0, bv0};
        av[tt][1] = f32x4{bv1, bv1, bv1, bv1};
      }
#pragma unroll
      for (int kt = 0; kt < 6; ++kt) {
        bf16x8 xf0 = *(const bf16x8*)(xr + kt * 64);
        bf16x8 xf1 = *(const bf16x8*)(xr + 6400 + kt * 64);
        bf16x8 xf2 = *(const bf16x8*)(xr + 12800 + kt * 64);
        bf16x8 xf3 = *(const bf16x8*)(xr + 19200 + kt * 64);
        bf16x8 w0 = *(const bf16x8*)(wv0 + kt * 32);
        bf16x8 w1 = *(const bf16x8*)(wv1 + kt * 32);
        av[0][0] = MFMA16(xf0, w0, av[0][0], 0, 0, 0);
        av[0][1] = MFMA16(xf0, w1, av[0][1], 0, 0, 0);
        av[1][0] = MFMA16(xf1, w0, av[1][0], 0, 0, 0);
        av[1][1] = MFMA16(xf1, w1, av[1][1], 0, 0, 0);
        av[2][0] = MFMA16(xf2, w0, av[2][0], 0, 0, 0);
        av[2][1] = MFMA16(xf2, w1, av[2][1], 0, 0, 0);
        av[3][0] = MFMA16(xf3, w0, av[3][0], 0, 0, 0);
        av[3][1] = MFMA16(xf3, w1, av[3][1], 0, 0, 0);
      }
#pragma unroll
      for (int dt = 0; dt < 2; ++dt)
#pragma unroll
        for (int kh = 0; kh < 2; ++kh)
          own[dt * 2 + kh] = va[dt][kh] = xpose(av[2 * kh][dt], av[2 * kh + 1][dt]);
    }
  }
  __syncthreads();  // all x reads done -> exchange region may overlay x
  {
    char* ew = exch + hl * 8192 + half * 4096 + lane * 16;
#pragma unroll
    for (int f = 0; f < 4; ++f) *(bf16x8*)(ew + f * 1024) = own[f];
  }
  __syncthreads();
  {
    const char* er = exch + hl * 8192 + (half ^ 1) * 4096 + lane * 16;
    if (half == 0) {
#pragma unroll
      for (int f = 0; f < 4; ++f) va[f >> 1][f & 1] = *(const bf16x8*)(er + f * 1024);
    } else {
#pragma unroll
      for (int f = 0; f < 4; ++f) ka[f] = *(const bf16x8*)(er + f * 1024);
    }
  }

  // ---------- S = K @ Q^T (base-2 scaled) with bias as C operand; softmax ----------
  bf16x8 pbf[2][2];
  float linv[2];
  {
    const f32x4* bias4 = (const f32x4*)biasar + (size_t)(head * 16 + half * 2) * 64 + lane;
    f32x4 s[4][2];
#pragma unroll
    for (int mt = 0; mt < 4; ++mt)
#pragma unroll
      for (int n2 = 0; n2 < 2; ++n2)
        s[mt][n2] = MFMA16(ka[mt], qb[n2], bias4[(mt * 4 + n2) * 64], 0, 0, 0);
#pragma unroll
    for (int n2 = 0; n2 < 2; ++n2) {
      float mx = fmaxf(fmaxf(fmaxf(s[0][n2][0], s[0][n2][1]), fmaxf(s[0][n2][2], s[0][n2][3])),
                       fmaxf(fmaxf(s[1][n2][0], s[1][n2][1]), fmaxf(s[1][n2][2], s[1][n2][3])));
      mx = fmaxf(mx, fmaxf(fmaxf(fmaxf(s[2][n2][0], s[2][n2][1]), fmaxf(s[2][n2][2], s[2][n2][3])),
                           fmaxf(fmaxf(s[3][n2][0], s[3][n2][1]), fmaxf(s[3][n2][2], s[3][n2][3]))));
      mx = fmaxf(mx, __shfl_xor(mx, 16));
      mx = fmaxf(mx, __shfl_xor(mx, 32));
      float sum = 0.0f;
#pragma unroll
      for (int mt = 0; mt < 4; ++mt)
#pragma unroll
        for (int r = 0; r < 4; ++r) {
          float e = __builtin_exp2f(s[mt][n2][r] - mx);  // log2e folded upstream
          s[mt][n2][r] = e;
          sum += e;
        }
      sum += __shfl_xor(sum, 16);
      sum += __shfl_xor(sum, 32);
      linv[n2] = 1.0f / sum;
    }
#pragma unroll
    for (int n2 = 0; n2 < 2; ++n2) {
      pbf[0][n2] = xpose(s[0][n2], s[1][n2]);
      pbf[1][n2] = xpose(s[2][n2], s[3][n2]);
    }
  }

  // ---------- O^T = V^T @ P^T, scale, dump frags ----------
  f32x4 o[2][2];
#pragma unroll
  for (int dt = 0; dt < 2; ++dt)
#pragma unroll
    for (int n2 = 0; n2 < 2; ++n2) o[dt][n2] = (f32x4)0.0f;
#pragma unroll
  for (int mh = 0; mh < 2; ++mh)
#pragma unroll
    for (int n2 = 0; n2 < 2; ++n2)
#pragma unroll
      for (int dt = 0; dt < 2; ++dt) o[dt][n2] = MFMA16(va[dt][mh], pbf[mh][n2], o[dt][n2], 0, 0, 0);

  uint2* dst = (uint2*)osout + ((size_t)((b * 6 + head) * 2 + half) * 4) * 64 + lane;
#pragma unroll
  for (int dt = 0; dt < 2; ++dt)
#pragma unroll
    for (int n2 = 0; n2 < 2; ++n2) {
#pragma unroll
      for (int r = 0; r < 4; ++r) o[dt][n2][r] *= linv[n2];
      dst[(dt * 2 + n2) * 64] = pk4(o[dt][n2]);
    }
}

// proj: block = 1 window (64 tokens), 4 waves; wave w covers f in [w*48, w*48+48).
__global__ void __launch_bounds__(256, 4) proj_kernel(
    const unsigned short* __restrict__ osin, const unsigned short* __restrict__ wproj,
    const float* __restrict__ proj_b, float* __restrict__ out) {
  __shared__ __align__(16) char smem[24576];
  const int b = blockIdx.x;
  const int tid = threadIdx.x;
  const int w = tid >> 6;  // 0..3
  const int lane = tid & 63;
  const int g = lane >> 4;
  const int c = lane & 15;

  // ---------- decode frag dump -> [tok][d] swizzled LDS ----------
  {
    const uint2* src = (const uint2*)osin + (size_t)b * 3072;
#pragma unroll
    for (int it = 0; it < 12; ++it) {
      int i = tid + it * 256;
      int ls = i & 63;
      int f = (i >> 6) & 3;  // dt*2 + n2
      int unit = i >> 8;     // head*2 + half
      int head = unit >> 1, half = unit & 1;
      int dt = f >> 1, n2 = f & 1;
      int tok = half * 32 + n2 * 16 + (ls & 15);
      int d0 = head * 32 + dt * 16 + 4 * (ls >> 4);
      uint2 v = src[i];
      *(uint2*)(smem + tok * 384 + (((d0 >> 3) ^ (tok & 7)) << 4) + (d0 & 7) * 2) = v;
    }
  }
  __syncthreads();

  // ---------- GEMM: out = Os @ wproj^T + b ----------
  f32x4 acc[4][3];
#pragma unroll
  for (int mt = 0; mt < 4; ++mt)
#pragma unroll
    for (int ft = 0; ft < 3; ++ft) acc[mt][ft] = (f32x4)0.0f;
#pragma unroll
  for (int kt = 0; kt < 6; ++kt) {
    bf16x8 wf[3];
#pragma unroll
    for (int ft = 0; ft < 3; ++ft)
      wf[ft] = *(const bf16x8*)(wproj + (size_t)(w * 48 + ft * 16 + c) * 192 + kt * 32 + 8 * g);
#pragma unroll
    for (int mt = 0; mt < 4; ++mt) {
      bf16x8 of = *(const bf16x8*)(smem + (mt * 16 + c) * 384 + (((kt * 4 + g) ^ (c & 7)) << 4));
#pragma unroll
      for (int ft = 0; ft < 3; ++ft) acc[mt][ft] = MFMA16(of, wf[ft], acc[mt][ft], 0, 0, 0);
    }
  }
  float* outb = out + (size_t)b * 12288;
#pragma unroll
  for (int ft = 0; ft < 3; ++ft) {
    float pbv = proj_b[w * 48 + ft * 16 + c];
#pragma unroll
    for (int mt = 0; mt < 4; ++mt)
#pragma unroll
      for (int r = 0; r < 4; ++r)
        outb[(mt * 16 + 4 * g + r) * 192 + w * 48 + ft * 16 + c] = acc[mt][ft][r] + pbv;
  }
}

// ===================== FUSED FALLBACK (R4-based; exp2 tables) =====================
#define XFRAGOLD(tt, kt) \
  (*(const bf16x8*)(xs + ((tt) * 16 + c) * 384 + ((((kt) * 4 + g) ^ (c & 7)) << 4)))

__global__ void __launch_bounds__(384, 3) win_attn(
    const float* __restrict__ x, const unsigned short* __restrict__ wqkv,
    const unsigned short* __restrict__ wproj, const float* __restrict__ biasar,
    const float* __restrict__ bq, const float* __restrict__ proj_b, float* __restrict__ out) {
  __shared__ __align__(16) char smem[24576];
  const int b = blockIdx.x;
  const int tid = threadIdx.x;
  const int w = tid >> 6;
  const int lane = tid & 63;
  const int g = lane >> 4;
  const int c = lane & 15;
  char* xs = smem;

  {
    const float* xb = x + (size_t)b * 12288;
#pragma unroll
    for (int it = 0; it < 8; ++it) {
      int idx = tid + it * 384;
      int tok = idx / 48, c4 = idx % 48;
      float4 v = *(const float4*)(xb + tok * 192 + c4 * 4);
      *(uint2*)(xs + tok * 384 + (((c4 >> 1) ^ (tok & 7)) << 4) + (c4 & 1) * 8) =
          make_uint2(pk2(v.x, v.y), pk2(v.z, v.w));
    }
  }
  __syncthreads();

  bf16x8 qb[4];
  {
    f32x4 acc[2][4];
#pragma unroll
    for (int dt = 0; dt < 2; ++dt)
#pragma unroll
      for (int tt = 0; tt < 4; ++tt) acc[dt][tt] = (f32x4)0.0f;
#pragma unroll
    for (int kt = 0; kt < 6; ++kt) {
      bf16x8 wf[2];
#pragma unroll
      for (int dt = 0; dt < 2; ++dt)
        wf[dt] = *(const bf16x8*)(wqkv + (size_t)(w * 32 + dt * 16 + c) * 192 + kt * 32 + 8 * g);
#pragma unroll
      for (int tt = 0; tt < 4; ++tt) {
        bf16x8 xf = XFRAGOLD(tt, kt);
#pragma unroll
        for (int dt = 0; dt < 2; ++dt) acc[dt][tt] = MFMA16(wf[dt], xf, acc[dt][tt], 0, 0, 0);
      }
    }
#pragma unroll
    for (int dt = 0; dt < 2; ++dt)
#pragma unroll
      for (int r = 0; r < 4; ++r) {
        float bv = bq[w * 32 + dt * 16 + 4 * g + r];
#pragma unroll
        for (int tt = 0; tt < 4; ++tt) acc[dt][tt][r] += bv;
      }
#pragma unroll
    for (int nt = 0; nt < 4; ++nt) qb[nt] = xpose(acc[0][nt], acc[1][nt]);
  }

  bf16x8 ka[4];
  {
    f32x4 acc[2][4];
#pragma unroll
    for (int dt = 0; dt < 2; ++dt)
#pragma unroll
      for (int tt = 0; tt < 4; ++tt) acc[dt][tt] = (f32x4)0.0f;
#pragma unroll
    for (int kt = 0; kt < 6; ++kt) {
      bf16x8 wf[2];
#pragma unroll
      for (int dt = 0; dt < 2; ++dt)
        wf[dt] =
            *(const bf16x8*)(wqkv + (size_t)(192 + w * 32 + dt * 16 + c) * 192 + kt * 32 + 8 * g);
#pragma unroll
      for (int tt = 0; tt < 4; ++tt) {
        bf16x8 xf = XFRAGOLD(tt, kt);
#pragma unroll
        for (int dt = 0; dt < 2; ++dt) acc[dt][tt] = MFMA16(wf[dt], xf, acc[dt][tt], 0, 0, 0);
      }
    }
#pragma unroll
    for (int dt = 0; dt < 2; ++dt)
#pragma unroll
      for (int r = 0; r < 4; ++r) {
        float bv = bq[192 + w * 32 + dt * 16 + 4 * g + r];
#pragma unroll
        for (int tt = 0; tt < 4; ++tt) acc[dt][tt][r] += bv;
      }
#pragma unroll
    for (int mt = 0; mt < 4; ++mt) ka[mt] = xpose(acc[0][mt], acc[1][mt]);
  }

  bf16x8 pbf[2][4];
  float linv[4];
  const f32x4* bias4 = (const f32x4*)biasar;
#pragma unroll
  for (int h = 0; h < 2; ++h) {
    f32x4 s[4][2];
#pragma unroll
    for (int mt = 0; mt < 4; ++mt)
#pragma unroll
      for (int n2 = 0; n2 < 2; ++n2) {
        int nt = h * 2 + n2;
        f32x4 t = MFMA16(ka[mt], qb[nt], (f32x4)0.0f, 0, 0, 0);
        s[mt][n2] = t + bias4[(w * 16 + mt * 4 + nt) * 64 + lane];
      }
#pragma unroll
    for (int n2 = 0; n2 < 2; ++n2) {
      int nt = h * 2 + n2;
      float mx = -1e30f;
#pragma unroll
      for (int mt = 0; mt < 4; ++mt)
#pragma unroll
        for (int r = 0; r < 4; ++r) mx = fmaxf(mx, s[mt][n2][r]);
      mx = fmaxf(mx, __shfl_xor(mx, 16));
      mx = fmaxf(mx, __shfl_xor(mx, 32));
      float sum = 0.0f;
#pragma unroll
      for (int mt = 0; mt < 4; ++mt)
#pragma unroll
        for (int r = 0; r < 4; ++r) {
          float e = __builtin_exp2f(s[mt][n2][r] - mx);
          s[mt][n2][r] = e;
          sum += e;
        }
      sum += __shfl_xor(sum, 16);
      sum += __shfl_xor(sum, 32);
      linv[nt] = 1.0f / sum;
    }
#pragma unroll
    for (int n2 = 0; n2 < 2; ++n2) {
      pbf[0][h * 2 + n2] = xpose(s[0][n2], s[1][n2]);
      pbf[1][h * 2 + n2] = xpose(s[2][n2], s[3][n2]);
    }
  }

  bf16x8 va[2][2];
  {
    f32x4 acc[4][2];
#pragma unroll
    for (int mt = 0; mt < 4; ++mt)
#pragma unroll
      for (int dt = 0; dt < 2; ++dt) acc[mt][dt] = (f32x4)0.0f;
#pragma unroll
    for (int kt = 0; kt < 6; ++kt) {
      bf16x8 wf[2];
#pragma unroll
      for (int dt = 0; dt < 2; ++dt)
        wf[dt] =
            *(const bf16x8*)(wqkv + (size_t)(384 + w * 32 + dt * 16 + c) * 192 + kt * 32 + 8 * g);
#pragma unroll
      for (int tt = 0; tt < 4; ++tt) {
        bf16x8 xf = XFRAGOLD(tt, kt);
#pragma unroll
        for (int dt = 0; dt < 2; ++dt) acc[tt][dt] = MFMA16(xf, wf[dt], acc[tt][dt], 0, 0, 0);
      }
    }
#pragma unroll
    for (int dt = 0; dt < 2; ++dt) {
      float bv = bq[384 + w * 32 + dt * 16 + c];
#pragma unroll
      for (int mt = 0; mt < 4; ++mt)
#pragma unroll
        for (int r = 0; r < 4; ++r) acc[mt][dt][r] += bv;
    }
#pragma unroll
    for (int dt = 0; dt < 2; ++dt)
#pragma unroll
      for (int kh = 0; kh < 2; ++kh) va[dt][kh] = xpose(acc[2 * kh][dt], acc[2 * kh + 1][dt]);
  }

  f32x4 o[2][4];
#pragma unroll
  for (int dt = 0; dt < 2; ++dt)
#pragma unroll
    for (int nt = 0; nt < 4; ++nt) o[dt][nt] = (f32x4)0.0f;
#pragma unroll
  for (int mh = 0; mh < 2; ++mh)
#pragma unroll
    for (int nt = 0; nt < 4; ++nt)
#pragma unroll
      for (int dt = 0; dt < 2; ++dt) o[dt][nt] = MFMA16(va[dt][mh], pbf[mh][nt], o[dt][nt], 0, 0, 0);
#pragma unroll
  for (int dt = 0; dt < 2; ++dt)
#pragma unroll
    for (int nt = 0; nt < 4; ++nt)
#pragma unroll
      for (int r = 0; r < 4; ++r) o[dt][nt][r] *= linv[nt];

  __syncthreads();
#pragma unroll
  for (int dt = 0; dt < 2; ++dt)
#pragma unroll
    for (int nt = 0; nt < 4; ++nt)
      *(uint2*)(xs + (nt * 16 + c) * 384 + (((w * 4 + dt * 2 + (g >> 1)) ^ (c & 7)) << 4) +
                (g & 1) * 8) =
          make_uint2(pk2(o[dt][nt][0], o[dt][nt][1]), pk2(o[dt][nt][2], o[dt][nt][3]));
  __syncthreads();

  f32x4 accP[4][2];
#pragma unroll
  for (int mt = 0; mt < 4; ++mt)
#pragma unroll
    for (int ft = 0; ft < 2; ++ft) accP[mt][ft] = (f32x4)0.0f;
#pragma unroll
  for (int kt = 0; kt < 6; ++kt) {
    bf16x8 wp[2];
#pragma unroll
    for (int ft = 0; ft < 2; ++ft)
      wp[ft] = *(const bf16x8*)(wproj + (size_t)(w * 32 + ft * 16 + c) * 192 + kt * 32 + 8 * g);
#pragma unroll
    for (int mt = 0; mt < 4; ++mt) {
      bf16x8 of = *(const bf16x8*)(xs + (mt * 16 + c) * 384 + (((kt * 4 + g) ^ (c & 7)) << 4));
#pragma unroll
      for (int ft = 0; ft < 2; ++ft) accP[mt][ft] = MFMA16(of, wp[ft], accP[mt][ft], 0, 0, 0);
    }
  }
  float pb0 = proj_b[w * 32 + c];
  float pb1 = proj_b[w * 32 + 16 + c];
  float* outb = out + (size_t)b * 12288;
#pragma unroll
  for (int mt = 0; mt < 4; ++mt)
#pragma unroll
    for (int ft = 0; ft < 2; ++ft) {
      float pbv = ft ? pb1 : pb0;
#pragma unroll
      for (int r = 0; r < 4; ++r)
        outb[(mt * 16 + 4 * g + r) * 192 + w * 32 + ft * 16 + c] = accP[mt][ft][r] + pbv;
    }
}

extern "C" void kernel_launch(void* const* d_in, const int* in_sizes, int n_in,
                              void* d_out, int out_size, void* d_ws, size_t ws_size,
                              hipStream_t stream) {
  const float* x = (const float*)d_in[0];
  const float* qkv_w = (const float*)d_in[1];
  const float* qkv_b = (const float*)d_in[2];
  const float* proj_w = (const float*)d_in[3];
  const float* proj_b = (const float*)d_in[4];
  const float* rpb = (const float*)d_in[5];
  char* ws = (char*)d_ws;
  unsigned short* wqkv = (unsigned short*)ws;
  unsigned short* wproj = (unsigned short*)(ws + 221184);
  float* biasar = (float*)(ws + 294912);
  float* bqv = (float*)(ws + 393216);

  prep_kernel<<<432, 256, 0, stream>>>(qkv_w, qkv_b, proj_w, rpb, wqkv, wproj, biasar, bqv);

  if (ws_size >= (size_t)WS_NEED) {
    unsigned short* osbuf = (unsigned short*)(ws + OS_OFF);
    win_attn4<<<12288, 256, 0, stream>>>(x, wqkv, biasar, bqv, osbuf);
    proj_kernel<<<4096, 256, 0, stream>>>(osbuf, wproj, proj_b, (float*)d_out);
  } else {
    win_attn<<<4096, 384, 0, stream>>>(x, wqkv, wproj, biasar, bqv, proj_b, (float*)d_out);
  }
}

// Round 10
// 271.870 us; speedup vs baseline: 1.2323x; 1.0643x over previous
//
#include <hip/hip_runtime.h>
#include <hip/hip_bf16.h>

typedef short bf16x8 __attribute__((ext_vector_type(8)));
typedef float f32x4 __attribute__((ext_vector_type(4)));
typedef unsigned int u32;
typedef unsigned int u32x2 __attribute__((ext_vector_type(2)));

#define MFMA16 __builtin_amdgcn_mfma_f32_16x16x32_bf16
#define SCALE 0.17677669529663687f  // 1/sqrt(32)
#define LOG2E 1.4426950408889634f

// ws layout (bytes):
//   wqkv  bf16 [576][192]          @ 0        (221184)   (q rows pre-scaled by SCALE*LOG2E)
//   wproj bf16 [192][192]          @ 221184   (73728)
//   biasar f32 [6][16][64][4]      @ 294912   (98304)    (pre-scaled by LOG2E)
//   bq    f32  [576]               @ 393216   (2304)
//   Os    frag dump                @ 395520   (100663296)   [split path only]
#define OS_OFF 395520
#define WS_NEED (395520 + 100663296)

__device__ __forceinline__ unsigned short f2b(float x) {
  u32 u = __float_as_uint(x);
  u = (u + 0x7FFFu + ((u >> 16) & 1u)) >> 16;
  return (unsigned short)u;
}
__device__ __forceinline__ u32 pk2(float a, float b) {
  __hip_bfloat162 h = __float22bfloat162_rn(float2{a, b});
  return *(u32*)&h;
}
__device__ __forceinline__ uint2 pk4(f32x4 v) {
  return make_uint2(pk2(v[0], v[1]), pk2(v[2], v[3]));
}

// C-frag pair -> A/B-frag bf16x8 via 2x v_permlane16_swap (VALU). The k-dim
// carries a fixed permutation pi; pi is identical for every operand produced
// by this helper, so it cancels inside MFMA dot products.
__device__ __forceinline__ bf16x8 xpose(f32x4 a0, f32x4 a1) {
  u32 s0 = pk2(a0[0], a0[1]);
  u32 s1 = pk2(a0[2], a0[3]);
  u32 s2 = pk2(a1[0], a1[1]);
  u32 s3 = pk2(a1[2], a1[3]);
  u32x2 r0 = __builtin_amdgcn_permlane16_swap(s0, s2, false, false);
  u32x2 r1 = __builtin_amdgcn_permlane16_swap(s1, s3, false, false);
  union {
    u32 w[4];
    bf16x8 v;
  } u;
  u.w[0] = r0[0];
  u.w[1] = r1[0];
  u.w[2] = r0[1];
  u.w[3] = r1[1];
  return u.v;
}

__global__ void prep_kernel(const float* __restrict__ qkv_w, const float* __restrict__ qkv_b,
                            const float* __restrict__ proj_w, const float* __restrict__ rpb,
                            unsigned short* __restrict__ wqkv, unsigned short* __restrict__ wproj,
                            float* __restrict__ biasar, float* __restrict__ bq) {
  int i0 = blockIdx.x * blockDim.x + threadIdx.x;
  int stride = gridDim.x * blockDim.x;
  for (int i = i0; i < 576 * 192; i += stride) {
    float v = qkv_w[i];
    if (i < 192 * 192) v *= SCALE * LOG2E;  // q rows: fold softmax scale + log2(e)
    wqkv[i] = f2b(v);
  }
  for (int i = i0; i < 192 * 192; i += stride) wproj[i] = f2b(proj_w[i]);
  for (int i = i0; i < 576; i += stride) {
    float v = qkv_b[i];
    if (i < 192) v *= SCALE * LOG2E;
    bq[i] = v;
  }
  for (int i = i0; i < 6 * 16 * 64 * 4; i += stride) {
    int r = i & 3;
    int lane = (i >> 2) & 63;
    int fid = (i >> 8) & 15;
    int h = i >> 12;
    int mt = fid >> 2, nt = fid & 3;
    int m = mt * 16 + (lane >> 4) * 4 + r;
    int n = nt * 16 + (lane & 15);
    int idx = ((n >> 3) - (m >> 3) + 7) * 15 + ((n & 7) - (m & 7) + 7);
    biasar[i] = rpb[idx * 6 + h] * LOG2E;
  }
}

// ===================== SPLIT PATH =====================
// win_attn4 (R9 structure + load pipelining): block = (window, head-pair) =
// 4 waves; wave = (head in pair, q-half). half0 computes K, half1 V; frags
// exchanged via LDS. (256,3): ~170-reg cap gives the compiler room to keep
// all 12 staging float4 loads AND the weight fragments in flight (R9's
// 128-cap serialized them -> ~12 dependent HBM waits on the block critical
// path). Q weights issued BEFORE the staging barrier; K/V weights right
// after it. Exchange buffer overlays x (dead after K/V pass).
__global__ void __launch_bounds__(256, 3) win_attn4(
    const float* __restrict__ x, const unsigned short* __restrict__ wqkv,
    const float* __restrict__ biasar, const float* __restrict__ bq,
    unsigned short* __restrict__ osout) {
  __shared__ __align__(16) char smem[25600];
  const int bid = blockIdx.x;
  const int xcd = bid & 7;
  const int local = bid >> 3;     // 0..1535
  const int wl = local / 3;       // 0..511
  const int hg = local - wl * 3;  // head pair 0..2
  const int b = xcd * 512 + wl;   // window
  const int tid = threadIdx.x;
  const int wv = tid >> 6;       // 0..3
  const int hl = wv >> 1;        // head within pair
  const int head = hg * 2 + hl;  // global head
  const int half = wv & 1;       // q-half
  const int lane = tid & 63;
  const int g = lane >> 4;
  const int c = lane & 15;
  char* xs = smem;
  char* exch = smem;  // overlays x (x dead after K/V pass; barrier-separated)

  // ---------- phase 1: issue ALL staging loads (48 VGPRs in flight) ----------
  float4 v[12];
  {
    const float* xb = x + (size_t)b * 12288;
#pragma unroll
    for (int it = 0; it < 12; ++it) {
      int idx = tid + it * 256;  // float4 index in [0,3072)
      int tok = idx / 48, c4 = idx - tok * 48;
      v[it] = *(const float4*)(xb + tok * 192 + c4 * 4);
    }
  }

  // ---------- issue Q-pass weight loads (independent of LDS; hide under drain) ----------
  bf16x8 wqf[2][6];
  {
    const unsigned short* wq0 = wqkv + (size_t)(head * 32 + c) * 192 + 8 * g;
    const unsigned short* wq1 = wq0 + 16 * 192;
#pragma unroll
    for (int kt = 0; kt < 6; ++kt) {
      wqf[0][kt] = *(const bf16x8*)(wq0 + kt * 32);
      wqf[1][kt] = *(const bf16x8*)(wq1 + kt * 32);
    }
  }

  // ---------- phase 2: convert + write staging (rows padded to 400B) ----------
  {
#pragma unroll
    for (int it = 0; it < 12; ++it) {
      int idx = tid + it * 256;
      int tok = idx / 48, c4 = idx - tok * 48;
      *(uint2*)(xs + tok * 400 + c4 * 8) =
          make_uint2(pk2(v[it].x, v[it].y), pk2(v[it].z, v[it].w));
    }
  }
  __syncthreads();

  // ---------- issue K/V weight loads (overlap with Q compute) ----------
  bf16x8 wkv[2][6];
  {
    const unsigned short* w0 =
        wqkv + (size_t)((half ? 384 : 192) + head * 32 + c) * 192 + 8 * g;
    const unsigned short* w1 = w0 + 16 * 192;
#pragma unroll
    for (int kt = 0; kt < 6; ++kt) {
      wkv[0][kt] = *(const bf16x8*)(w0 + kt * 32);
      wkv[1][kt] = *(const bf16x8*)(w1 + kt * 32);
    }
  }

  // ---------- Q pass (this wave's 32 query tokens; bias as C-init) ----------
  bf16x8 qb[2];
  {
    f32x4 a00 = *(const f32x4*)(bq + head * 32 + 4 * g);
    f32x4 a10 = *(const f32x4*)(bq + head * 32 + 16 + 4 * g);
    f32x4 a01 = a00, a11 = a10;
    const char* xr = xs + c * 400 + g * 16 + half * 12800;
#pragma unroll
    for (int kt = 0; kt < 6; ++kt) {
      bf16x8 x0 = *(const bf16x8*)(xr + kt * 64);
      bf16x8 x1 = *(const bf16x8*)(xr + 6400 + kt * 64);
      a00 = MFMA16(wqf[0][kt], x0, a00, 0, 0, 0);
      a10 = MFMA16(wqf[1][kt], x0, a10, 0, 0, 0);
      a01 = MFMA16(wqf[0][kt], x1, a01, 0, 0, 0);
      a11 = MFMA16(wqf[1][kt], x1, a11, 0, 0, 0);
    }
    qb[0] = xpose(a00, a10);
    qb[1] = xpose(a01, a11);
  }

  // ---------- K xor V pass (wave-uniform branch) ----------
  bf16x8 ka[4], va[2][2], own[4];
  {
    const char* xr = xs + c * 400 + g * 16;
    if (half == 0) {
      f32x4 bk0 = *(const f32x4*)(bq + 192 + head * 32 + 4 * g);
      f32x4 bk1 = *(const f32x4*)(bq + 192 + head * 32 + 16 + 4 * g);
      f32x4 ak[2][4];
#pragma unroll
      for (int tt = 0; tt < 4; ++tt) {
        ak[0][tt] = bk0;
        ak[1][tt] = bk1;
      }
#pragma unroll
      for (int kt = 0; kt < 6; ++kt) {
        bf16x8 xf0 = *(const bf16x8*)(xr + kt * 64);
        bf16x8 xf1 = *(const bf16x8*)(xr + 6400 + kt * 64);
        bf16x8 xf2 = *(const bf16x8*)(xr + 12800 + kt * 64);
        bf16x8 xf3 = *(const bf16x8*)(xr + 19200 + kt * 64);
        ak[0][0] = MFMA16(wkv[0][kt], xf0, ak[0][0], 0, 0, 0);
        ak[1][0] = MFMA16(wkv[1][kt], xf0, ak[1][0], 0, 0, 0);
        ak[0][1] = MFMA16(wkv[0][kt], xf1, ak[0][1], 0, 0, 0);
        ak[1][1] = MFMA16(wkv[1][kt], xf1, ak[1][1], 0, 0, 0);
        ak[0][2] = MFMA16(wkv[0][kt], xf2, ak[0][2], 0, 0, 0);
        ak[1][2] = MFMA16(wkv[1][kt], xf2, ak[1][2], 0, 0, 0);
        ak[0][3] = MFMA16(wkv[0][kt], xf3, ak[0][3], 0, 0, 0);
        ak[1][3] = MFMA16(wkv[1][kt], xf3, ak[1][3], 0, 0, 0);
      }
#pragma unroll
      for (int mt = 0; mt < 4; ++mt) own[mt] = ka[mt] = xpose(ak[0][mt], ak[1][mt]);
    } else {
      float bv0 = bq[384 + head * 32 + c];
      float bv1 = bq[384 + head * 32 + 16 + c];
      f32x4 av[4][2];
#pragma unroll
      for (int tt = 0; tt < 4; ++tt) {
        av[tt][0] = f32x4{bv0, bv0, bv0, bv0};
        av[tt][1] = f32x4{bv1, bv1, bv1, bv1};
      }
#pragma unroll
      for (int kt = 0; kt < 6; ++kt) {
        bf16x8 xf0 = *(const bf16x8*)(xr + kt * 64);
        bf16x8 xf1 = *(const bf16x8*)(xr + 6400 + kt * 64);
        bf16x8 xf2 = *(const bf16x8*)(xr + 12800 + kt * 64);
        bf16x8 xf3 = *(const bf16x8*)(xr + 19200 + kt * 64);
        av[0][0] = MFMA16(xf0, wkv[0][kt], av[0][0], 0, 0, 0);
        av[0][1] = MFMA16(xf0, wkv[1][kt], av[0][1], 0, 0, 0);
        av[1][0] = MFMA16(xf1, wkv[0][kt], av[1][0], 0, 0, 0);
        av[1][1] = MFMA16(xf1, wkv[1][kt], av[1][1], 0, 0, 0);
        av[2][0] = MFMA16(xf2, wkv[0][kt], av[2][0], 0, 0, 0);
        av[2][1] = MFMA16(xf2, wkv[1][kt], av[2][1], 0, 0, 0);
        av[3][0] = MFMA16(xf3, wkv[0][kt], av[3][0], 0, 0, 0);
        av[3][1] = MFMA16(xf3, wkv[1][kt], av[3][1], 0, 0, 0);
      }
#pragma unroll
      for (int dt = 0; dt < 2; ++dt)
#pragma unroll
        for (int kh = 0; kh < 2; ++kh)
          own[dt * 2 + kh] = va[dt][kh] = xpose(av[2 * kh][dt], av[2 * kh + 1][dt]);
    }
  }
  // issue bias loads now (used after exchange; latency hides under LDS exchange)
  f32x4 bias[4][2];
  {
    const f32x4* bias4 = (const f32x4*)biasar + (size_t)(head * 16 + half * 2) * 64 + lane;
#pragma unroll
    for (int mt = 0; mt < 4; ++mt)
#pragma unroll
      for (int n2 = 0; n2 < 2; ++n2) bias[mt][n2] = bias4[(mt * 4 + n2) * 64];
  }
  __syncthreads();  // all x reads done -> exchange region may overlay x
  {
    char* ew = exch + hl * 8192 + half * 4096 + lane * 16;
#pragma unroll
    for (int f = 0; f < 4; ++f) *(bf16x8*)(ew + f * 1024) = own[f];
  }
  __syncthreads();
  {
    const char* er = exch + hl * 8192 + (half ^ 1) * 4096 + lane * 16;
    if (half == 0) {
#pragma unroll
      for (int f = 0; f < 4; ++f) va[f >> 1][f & 1] = *(const bf16x8*)(er + f * 1024);
    } else {
#pragma unroll
      for (int f = 0; f < 4; ++f) ka[f] = *(const bf16x8*)(er + f * 1024);
    }
  }

  // ---------- S = K @ Q^T (base-2 scaled) with bias as C operand; softmax ----------
  bf16x8 pbf[2][2];
  float linv[2];
  {
    f32x4 s[4][2];
#pragma unroll
    for (int mt = 0; mt < 4; ++mt)
#pragma unroll
      for (int n2 = 0; n2 < 2; ++n2)
        s[mt][n2] = MFMA16(ka[mt], qb[n2], bias[mt][n2], 0, 0, 0);
#pragma unroll
    for (int n2 = 0; n2 < 2; ++n2) {
      float mx = fmaxf(fmaxf(fmaxf(s[0][n2][0], s[0][n2][1]), fmaxf(s[0][n2][2], s[0][n2][3])),
                       fmaxf(fmaxf(s[1][n2][0], s[1][n2][1]), fmaxf(s[1][n2][2], s[1][n2][3])));
      mx = fmaxf(mx, fmaxf(fmaxf(fmaxf(s[2][n2][0], s[2][n2][1]), fmaxf(s[2][n2][2], s[2][n2][3])),
                           fmaxf(fmaxf(s[3][n2][0], s[3][n2][1]), fmaxf(s[3][n2][2], s[3][n2][3]))));
      mx = fmaxf(mx, __shfl_xor(mx, 16));
      mx = fmaxf(mx, __shfl_xor(mx, 32));
      float sum = 0.0f;
#pragma unroll
      for (int mt = 0; mt < 4; ++mt)
#pragma unroll
        for (int r = 0; r < 4; ++r) {
          float e = __builtin_exp2f(s[mt][n2][r] - mx);  // log2e folded upstream
          s[mt][n2][r] = e;
          sum += e;
        }
      sum += __shfl_xor(sum, 16);
      sum += __shfl_xor(sum, 32);
      linv[n2] = 1.0f / sum;
    }
#pragma unroll
    for (int n2 = 0; n2 < 2; ++n2) {
      pbf[0][n2] = xpose(s[0][n2], s[1][n2]);
      pbf[1][n2] = xpose(s[2][n2], s[3][n2]);
    }
  }

  // ---------- O^T = V^T @ P^T, scale, dump frags ----------
  f32x4 o[2][2];
#pragma unroll
  for (int dt = 0; dt < 2; ++dt)
#pragma unroll
    for (int n2 = 0; n2 < 2; ++n2) o[dt][n2] = (f32x4)0.0f;
#pragma unroll
  for (int mh = 0; mh < 2; ++mh)
#pragma unroll
    for (int n2 = 0; n2 < 2; ++n2)
#pragma unroll
      for (int dt = 0; dt < 2; ++dt) o[dt][n2] = MFMA16(va[dt][mh], pbf[mh][n2], o[dt][n2], 0, 0, 0);

  uint2* dst = (uint2*)osout + ((size_t)((b * 6 + head) * 2 + half) * 4) * 64 + lane;
#pragma unroll
  for (int dt = 0; dt < 2; ++dt)
#pragma unroll
    for (int n2 = 0; n2 < 2; ++n2) {
#pragma unroll
      for (int r = 0; r < 4; ++r) o[dt][n2][r] *= linv[n2];
      dst[(dt * 2 + n2) * 64] = pk4(o[dt][n2]);
    }
}

// proj: block = 1 window (64 tokens), 4 waves; wave w covers f in [w*48, w*48+48).
__global__ void __launch_bounds__(256, 4) proj_kernel(
    const unsigned short* __restrict__ osin, const unsigned short* __restrict__ wproj,
    const float* __restrict__ proj_b, float* __restrict__ out) {
  __shared__ __align__(16) char smem[24576];
  const int b = blockIdx.x;
  const int tid = threadIdx.x;
  const int w = tid >> 6;  // 0..3
  const int lane = tid & 63;
  const int g = lane >> 4;
  const int c = lane & 15;

  // ---------- decode frag dump -> [tok][d] swizzled LDS ----------
  {
    const uint2* src = (const uint2*)osin + (size_t)b * 3072;
#pragma unroll
    for (int it = 0; it < 12; ++it) {
      int i = tid + it * 256;
      int ls = i & 63;
      int f = (i >> 6) & 3;  // dt*2 + n2
      int unit = i >> 8;     // head*2 + half
      int head = unit >> 1, half = unit & 1;
      int dt = f >> 1, n2 = f & 1;
      int tok = half * 32 + n2 * 16 + (ls & 15);
      int d0 = head * 32 + dt * 16 + 4 * (ls >> 4);
      uint2 v = src[i];
      *(uint2*)(smem + tok * 384 + (((d0 >> 3) ^ (tok & 7)) << 4) + (d0 & 7) * 2) = v;
    }
  }
  __syncthreads();

  // ---------- GEMM: out = Os @ wproj^T + b ----------
  f32x4 acc[4][3];
#pragma unroll
  for (int mt = 0; mt < 4; ++mt)
#pragma unroll
    for (int ft = 0; ft < 3; ++ft) acc[mt][ft] = (f32x4)0.0f;
#pragma unroll
  for (int kt = 0; kt < 6; ++kt) {
    bf16x8 wf[3];
#pragma unroll
    for (int ft = 0; ft < 3; ++ft)
      wf[ft] = *(const bf16x8*)(wproj + (size_t)(w * 48 + ft * 16 + c) * 192 + kt * 32 + 8 * g);
#pragma unroll
    for (int mt = 0; mt < 4; ++mt) {
      bf16x8 of = *(const bf16x8*)(smem + (mt * 16 + c) * 384 + (((kt * 4 + g) ^ (c & 7)) << 4));
#pragma unroll
      for (int ft = 0; ft < 3; ++ft) acc[mt][ft] = MFMA16(of, wf[ft], acc[mt][ft], 0, 0, 0);
    }
  }
  float* outb = out + (size_t)b * 12288;
#pragma unroll
  for (int ft = 0; ft < 3; ++ft) {
    float pbv = proj_b[w * 48 + ft * 16 + c];
#pragma unroll
    for (int mt = 0; mt < 4; ++mt)
#pragma unroll
      for (int r = 0; r < 4; ++r)
        outb[(mt * 16 + 4 * g + r) * 192 + w * 48 + ft * 16 + c] = acc[mt][ft][r] + pbv;
  }
}

// ===================== FUSED FALLBACK (R4-based; exp2 tables) =====================
#define XFRAGOLD(tt, kt) \
  (*(const bf16x8*)(xs + ((tt) * 16 + c) * 384 + ((((kt) * 4 + g) ^ (c & 7)) << 4)))

__global__ void __launch_bounds__(384, 3) win_attn(
    const float* __restrict__ x, const unsigned short* __restrict__ wqkv,
    const unsigned short* __restrict__ wproj, const float* __restrict__ biasar,
    const float* __restrict__ bq, const float* __restrict__ proj_b, float* __restrict__ out) {
  __shared__ __align__(16) char smem[24576];
  const int b = blockIdx.x;
  const int tid = threadIdx.x;
  const int w = tid >> 6;
  const int lane = tid & 63;
  const int g = lane >> 4;
  const int c = lane & 15;
  char* xs = smem;

  {
    const float* xb = x + (size_t)b * 12288;
#pragma unroll
    for (int it = 0; it < 8; ++it) {
      int idx = tid + it * 384;
      int tok = idx / 48, c4 = idx % 48;
      float4 v = *(const float4*)(xb + tok * 192 + c4 * 4);
      *(uint2*)(xs + tok * 384 + (((c4 >> 1) ^ (tok & 7)) << 4) + (c4 & 1) * 8) =
          make_uint2(pk2(v.x, v.y), pk2(v.z, v.w));
    }
  }
  __syncthreads();

  bf16x8 qb[4];
  {
    f32x4 acc[2][4];
#pragma unroll
    for (int dt = 0; dt < 2; ++dt)
#pragma unroll
      for (int tt = 0; tt < 4; ++tt) acc[dt][tt] = (f32x4)0.0f;
#pragma unroll
    for (int kt = 0; kt < 6; ++kt) {
      bf16x8 wf[2];
#pragma unroll
      for (int dt = 0; dt < 2; ++dt)
        wf[dt] = *(const bf16x8*)(wqkv + (size_t)(w * 32 + dt * 16 + c) * 192 + kt * 32 + 8 * g);
#pragma unroll
      for (int tt = 0; tt < 4; ++tt) {
        bf16x8 xf = XFRAGOLD(tt, kt);
#pragma unroll
        for (int dt = 0; dt < 2; ++dt) acc[dt][tt] = MFMA16(wf[dt], xf, acc[dt][tt], 0, 0, 0);
      }
    }
#pragma unroll
    for (int dt = 0; dt < 2; ++dt)
#pragma unroll
      for (int r = 0; r < 4; ++r) {
        float bv = bq[w * 32 + dt * 16 + 4 * g + r];
#pragma unroll
        for (int tt = 0; tt < 4; ++tt) acc[dt][tt][r] += bv;
      }
#pragma unroll
    for (int nt = 0; nt < 4; ++nt) qb[nt] = xpose(acc[0][nt], acc[1][nt]);
  }

  bf16x8 ka[4];
  {
    f32x4 acc[2][4];
#pragma unroll
    for (int dt = 0; dt < 2; ++dt)
#pragma unroll
      for (int tt = 0; tt < 4; ++tt) acc[dt][tt] = (f32x4)0.0f;
#pragma unroll
    for (int kt = 0; kt < 6; ++kt) {
      bf16x8 wf[2];
#pragma unroll
      for (int dt = 0; dt < 2; ++dt)
        wf[dt] =
            *(const bf16x8*)(wqkv + (size_t)(192 + w * 32 + dt * 16 + c) * 192 + kt * 32 + 8 * g);
#pragma unroll
      for (int tt = 0; tt < 4; ++tt) {
        bf16x8 xf = XFRAGOLD(tt, kt);
#pragma unroll
        for (int dt = 0; dt < 2; ++dt) acc[dt][tt] = MFMA16(wf[dt], xf, acc[dt][tt], 0, 0, 0);
      }
    }
#pragma unroll
    for (int dt = 0; dt < 2; ++dt)
#pragma unroll
      for (int r = 0; r < 4; ++r) {
        float bv = bq[192 + w * 32 + dt * 16 + 4 * g + r];
#pragma unroll
        for (int tt = 0; tt < 4; ++tt) acc[dt][tt][r] += bv;
      }
#pragma unroll
    for (int mt = 0; mt < 4; ++mt) ka[mt] = xpose(acc[0][mt], acc[1][mt]);
  }

  bf16x8 pbf[2][4];
  float linv[4];
  const f32x4* bias4 = (const f32x4*)biasar;
#pragma unroll
  for (int h = 0; h < 2; ++h) {
    f32x4 s[4][2];
#pragma unroll
    for (int mt = 0; mt < 4; ++mt)
#pragma unroll
      for (int n2 = 0; n2 < 2; ++n2) {
        int nt = h * 2 + n2;
        f32x4 t = MFMA16(ka[mt], qb[nt], (f32x4)0.0f, 0, 0, 0);
        s[mt][n2] = t + bias4[(w * 16 + mt * 4 + nt) * 64 + lane];
      }
#pragma unroll
    for (int n2 = 0; n2 < 2; ++n2) {
      int nt = h * 2 + n2;
      float mx = -1e30f;
#pragma unroll
      for (int mt = 0; mt < 4; ++mt)
#pragma unroll
        for (int r = 0; r < 4; ++r) mx = fmaxf(mx, s[mt][n2][r]);
      mx = fmaxf(mx, __shfl_xor(mx, 16));
      mx = fmaxf(mx, __shfl_xor(mx, 32));
      float sum = 0.0f;
#pragma unroll
      for (int mt = 0; mt < 4; ++mt)
#pragma unroll
        for (int r = 0; r < 4; ++r) {
          float e = __builtin_exp2f(s[mt][n2][r] - mx);
          s[mt][n2][r] = e;
          sum += e;
        }
      sum += __shfl_xor(sum, 16);
      sum += __shfl_xor(sum, 32);
      linv[nt] = 1.0f / sum;
    }
#pragma unroll
    for (int n2 = 0; n2 < 2; ++n2) {
      pbf[0][h * 2 + n2] = xpose(s[0][n2], s[1][n2]);
      pbf[1][h * 2 + n2] = xpose(s[2][n2], s[3][n2]);
    }
  }

  bf16x8 va[2][2];
  {
    f32x4 acc[4][2];
#pragma unroll
    for (int mt = 0; mt < 4; ++mt)
#pragma unroll
      for (int dt = 0; dt < 2; ++dt) acc[mt][dt] = (f32x4)0.0f;
#pragma unroll
    for (int kt = 0; kt < 6; ++kt) {
      bf16x8 wf[2];
#pragma unroll
      for (int dt = 0; dt < 2; ++dt)
        wf[dt] =
            *(const bf16x8*)(wqkv + (size_t)(384 + w * 32 + dt * 16 + c) * 192 + kt * 32 + 8 * g);
#pragma unroll
      for (int tt = 0; tt < 4; ++tt) {
        bf16x8 xf = XFRAGOLD(tt, kt);
#pragma unroll
        for (int dt = 0; dt < 2; ++dt) acc[tt][dt] = MFMA16(xf, wf[dt], acc[tt][dt], 0, 0, 0);
      }
    }
#pragma unroll
    for (int dt = 0; dt < 2; ++dt) {
      float bv = bq[384 + w * 32 + dt * 16 + c];
#pragma unroll
      for (int mt = 0; mt < 4; ++mt)
#pragma unroll
        for (int r = 0; r < 4; ++r) acc[mt][dt][r] += bv;
    }
#pragma unroll
    for (int dt = 0; dt < 2; ++dt)
#pragma unroll
      for (int kh = 0; kh < 2; ++kh) va[dt][kh] = xpose(acc[2 * kh][dt], acc[2 * kh + 1][dt]);
  }

  f32x4 o[2][4];
#pragma unroll
  for (int dt = 0; dt < 2; ++dt)
#pragma unroll
    for (int nt = 0; nt < 4; ++nt) o[dt][nt] = (f32x4)0.0f;
#pragma unroll
  for (int mh = 0; mh < 2; ++mh)
#pragma unroll
    for (int nt = 0; nt < 4; ++nt)
#pragma unroll
      for (int dt = 0; dt < 2; ++dt) o[dt][nt] = MFMA16(va[dt][mh], pbf[mh][nt], o[dt][nt], 0, 0, 0);
#pragma unroll
  for (int dt = 0; dt < 2; ++dt)
#pragma unroll
    for (int nt = 0; nt < 4; ++nt)
#pragma unroll
      for (int r = 0; r < 4; ++r) o[dt][nt][r] *= linv[nt];

  __syncthreads();
#pragma unroll
  for (int dt = 0; dt < 2; ++dt)
#pragma unroll
    for (int nt = 0; nt < 4; ++nt)
      *(uint2*)(xs + (nt * 16 + c) * 384 + (((w * 4 + dt * 2 + (g >> 1)) ^ (c & 7)) << 4) +
                (g & 1) * 8) =
          make_uint2(pk2(o[dt][nt][0], o[dt][nt][1]), pk2(o[dt][nt][2], o[dt][nt][3]));
  __syncthreads();

  f32x4 accP[4][2];
#pragma unroll
  for (int mt = 0; mt < 4; ++mt)
#pragma unroll
    for (int ft = 0; ft < 2; ++ft) accP[mt][ft] = (f32x4)0.0f;
#pragma unroll
  for (int kt = 0; kt < 6; ++kt) {
    bf16x8 wp[2];
#pragma unroll
    for (int ft = 0; ft < 2; ++ft)
      wp[ft] = *(const bf16x8*)(wproj + (size_t)(w * 32 + ft * 16 + c) * 192 + kt * 32 + 8 * g);
#pragma unroll
    for (int mt = 0; mt < 4; ++mt) {
      bf16x8 of = *(const bf16x8*)(xs + (mt * 16 + c) * 384 + (((kt * 4 + g) ^ (c & 7)) << 4));
#pragma unroll
      for (int ft = 0; ft < 2; ++ft) accP[mt][ft] = MFMA16(of, wp[ft], accP[mt][ft], 0, 0, 0);
    }
  }
  float pb0 = proj_b[w * 32 + c];
  float pb1 = proj_b[w * 32 + 16 + c];
  float* outb = out + (size_t)b * 12288;
#pragma unroll
  for (int mt = 0; mt < 4; ++mt)
#pragma unroll
    for (int ft = 0; ft < 2; ++ft) {
      float pbv = ft ? pb1 : pb0;
#pragma unroll
      for (int r = 0; r < 4; ++r)
        outb[(mt * 16 + 4 * g + r) * 192 + w * 32 + ft * 16 + c] = accP[mt][ft][r] + pbv;
    }
}

extern "C" void kernel_launch(void* const* d_in, const int* in_sizes, int n_in,
                              void* d_out, int out_size, void* d_ws, size_t ws_size,
                              hipStream_t stream) {
  const float* x = (const float*)d_in[0];
  const float* qkv_w = (const float*)d_in[1];
  const float* qkv_b = (const float*)d_in[2];
  const float* proj_w = (const float*)d_in[3];
  const float* proj_b = (const float*)d_in[4];
  const float* rpb = (const float*)d_in[5];
  char* ws = (char*)d_ws;
  unsigned short* wqkv = (unsigned short*)ws;
  unsigned short* wproj = (unsigned short*)(ws + 221184);
  float* biasar = (float*)(ws + 294912);
  float* bqv = (float*)(ws + 393216);

  prep_kernel<<<432, 256, 0, stream>>>(qkv_w, qkv_b, proj_w, rpb, wqkv, wproj, biasar, bqv);

  if (ws_size >= (size_t)WS_NEED) {
    unsigned short* osbuf = (unsigned short*)(ws + OS_OFF);
    win_attn4<<<12288, 256, 0, stream>>>(x, wqkv, biasar, bqv, osbuf);
    proj_kernel<<<4096, 256, 0, stream>>>(osbuf, wproj, proj_b, (float*)d_out);
  } else {
    win_attn<<<4096, 384, 0, stream>>>(x, wqkv, wproj, biasar, bqv, proj_b, (float*)d_out);
  }
}